// Round 4
// baseline (394.237 us; speedup 1.0000x reference)
//
#include <hip/hip_runtime.h>
#include <hip/hip_bf16.h>

#define N_NODES 5000
#define N_EDGES 80000
#define HID_DIM 128
#define OUT_DIM 64
#define BATCH 8
#define M_ROWS 40000
#define NEG_SLOPE 0.2f
#define BUCKET 96   // fixed per-node capacity; deg~Poisson(16), P(>96)~0 (+20 sigma)
#define GRID_BLOCKS 512   // persistent grid; launch_bounds(256,3) -> capacity 768, 50% slack

// R3: fused persistent kernel with HAND-ROLLED grid barrier (regular launch, no
// cooperative API — R2's hipLaunchCooperativeKernel never executed: absmax 3.76e-2
// == all-zero output vs small-logit softmax ref). Phase math identical to proven
// 153.1us dispatch pipeline (r15+R1). Barrier counters zeroed by setup dispatch
// each iteration -> single-use counters, no sense reversal.

typedef unsigned short ushort_t;
typedef unsigned int uint_t;
typedef __attribute__((ext_vector_type(8))) short short8;  // 8 bf16 = 4 VGPRs
typedef __attribute__((ext_vector_type(4))) float f32x4;

__device__ __forceinline__ float bf16_to_f32(ushort_t u) {
  return __uint_as_float(((uint_t)u) << 16);
}
__device__ __forceinline__ ushort_t f32_to_bf16(float f) {
  uint_t u = __float_as_uint(f);
  return (ushort_t)((u + 0x7FFF + ((u >> 16) & 1)) >> 16);  // RNE
}

struct __attribute__((aligned(8))) us4 { ushort_t x, y, z, w; };

// ---- grid barrier: release-fence + arrive, spin, acquire-fence. Counter single-use. ----
__device__ __forceinline__ void grid_barrier(int* __restrict__ bar) {
  __syncthreads();
  if (threadIdx.x == 0) {
    __threadfence();  // agent-scope release: write back this XCD's L2
    __hip_atomic_fetch_add(bar, 1, __ATOMIC_RELAXED, __HIP_MEMORY_SCOPE_AGENT);
    while (__hip_atomic_load(bar, __ATOMIC_RELAXED, __HIP_MEMORY_SCOPE_AGENT) < GRID_BLOCKS)
      __builtin_amdgcn_s_sleep(2);
    __threadfence();  // agent-scope acquire: invalidate stale lines before reading
  }
  __syncthreads();
}

// ---------------- setup: zero cnt + pack W + zero barrier counters (one dispatch) --------
__global__ __launch_bounds__(256) void setup_kernel(const float* __restrict__ W1,
                                                    const float* __restrict__ W2,
                                                    int* __restrict__ cnt,
                                                    ushort_t* __restrict__ Bp1,
                                                    ushort_t* __restrict__ Bp2,
                                                    int* __restrict__ bar) {
  int bid = blockIdx.x;
  if (bid == 0 && threadIdx.x < 3) bar[threadIdx.x * 32] = 0;  // 3 counters, 128B apart
  if (bid < 20) {
    int i = bid * 256 + threadIdx.x;
    if (i < N_NODES) cnt[i] = 0;
    return;
  }
  int gid = (bid - 20) * 256 + threadIdx.x;  // 0..3071
  if (gid >= 3072) return;
  const float* W; ushort_t* Bp; int NC, idx;
  if (gid < 2048) { W = W1; Bp = Bp1; NC = 128; idx = gid; }
  else            { W = W2; Bp = Bp2; NC = 64;  idx = gid - 2048; }
  int l = idx & 63, tt = idx >> 6;
  int T = NC / 16;
  int kc = tt / T, t = tt % T;
  int col = t * 16 + (l & 15);
  int krow = kc * 32 + (l >> 4) * 8;
  short8 vv;
#pragma unroll
  for (int j = 0; j < 8; j++) vv[j] = (short)f32_to_bf16(W[(size_t)(krow + j) * NC + col]);
  *(short8*)(Bp + (size_t)idx * 8) = vv;
}

// ---------------- GEMM tile (identical math to proven gemm_mfma, r6..r15) ----------------
template <int NC, bool A_F32, bool C_BF16>
__device__ __forceinline__ void gemm_tile(const void* __restrict__ A,
                                          const ushort_t* __restrict__ Bp,
                                          void* __restrict__ C,
                                          const float* __restrict__ al,
                                          const float* __restrict__ ar,
                                          float* __restrict__ el,
                                          float* __restrict__ er,
                                          int tile) {
  constexpr int T = NC / 16;
  int wave = threadIdx.x >> 6, lane = threadIdx.x & 63;
  int q = lane >> 4, m = lane & 15;
  int r0 = tile * 64 + wave * 16;
  f32x4 acc[T];
#pragma unroll
  for (int t = 0; t < T; t++)
#pragma unroll
    for (int i = 0; i < 4; i++) acc[t][i] = 0.f;

  const short8* Bp8 = (const short8*)Bp;
  size_t arow = (size_t)(r0 + m) * 128;
#pragma unroll
  for (int kc = 0; kc < 4; kc++) {
    short8 af;
    if (A_F32) {
      const float* Ap = (const float*)A + arow + kc * 32 + q * 8;
      float4 v0 = *(const float4*)Ap;
      float4 v1 = *(const float4*)(Ap + 4);
      af[0] = (short)f32_to_bf16(v0.x); af[1] = (short)f32_to_bf16(v0.y);
      af[2] = (short)f32_to_bf16(v0.z); af[3] = (short)f32_to_bf16(v0.w);
      af[4] = (short)f32_to_bf16(v1.x); af[5] = (short)f32_to_bf16(v1.y);
      af[6] = (short)f32_to_bf16(v1.z); af[7] = (short)f32_to_bf16(v1.w);
    } else {
      const ushort_t* Ap = (const ushort_t*)A + arow + kc * 32 + q * 8;
      us4 a0 = *(const us4*)Ap;
      us4 a1 = *(const us4*)(Ap + 4);
      af[0] = (short)a0.x; af[1] = (short)a0.y; af[2] = (short)a0.z; af[3] = (short)a0.w;
      af[4] = (short)a1.x; af[5] = (short)a1.y; af[6] = (short)a1.z; af[7] = (short)a1.w;
    }
#pragma unroll
    for (int t = 0; t < T; t++) {
      short8 bf = Bp8[(kc * T + t) * 64 + lane];
      acc[t] = __builtin_amdgcn_mfma_f32_16x16x32_bf16(af, bf, acc[t], 0, 0, 0);
    }
  }
  // fused el/er from fp32 acc (pre-rounding), reduce over 16 m-lanes
  float sl[4] = {0.f, 0.f, 0.f, 0.f}, sr[4] = {0.f, 0.f, 0.f, 0.f};
#pragma unroll
  for (int t = 0; t < T; t++) {
    float alv = al[t * 16 + m];
    float arv = ar[t * 16 + m];
#pragma unroll
    for (int i = 0; i < 4; i++) { sl[i] += acc[t][i] * alv; sr[i] += acc[t][i] * arv; }
  }
#pragma unroll
  for (int o = 1; o < 16; o <<= 1) {
#pragma unroll
    for (int i = 0; i < 4; i++) {
      sl[i] += __shfl_xor(sl[i], o, 64);
      sr[i] += __shfl_xor(sr[i], o, 64);
    }
  }
  if (m == 0) {
#pragma unroll
    for (int i = 0; i < 4; i++) {
      el[r0 + q * 4 + i] = sl[i];
      er[r0 + q * 4 + i] = sr[i];
    }
  }
  // C store: row = r0 + q*4 + i, col = t*16 + m (m89-verified)
#pragma unroll
  for (int t = 0; t < T; t++)
#pragma unroll
    for (int i = 0; i < 4; i++) {
      size_t off = (size_t)(r0 + q * 4 + i) * NC + t * 16 + m;
      if (C_BF16) ((ushort_t*)C)[off] = f32_to_bf16(acc[t][i]);
      else        ((float*)C)[off] = acc[t][i];
    }
}

// ---------------- edge-softmax aggregation unit (identical math to proven agg_kernel) -----
template <int F, bool FINAL>
__device__ __forceinline__ void agg_unit(const void* __restrict__ z,
                                         const float* __restrict__ el,
                                         const float* __restrict__ er,
                                         const float* __restrict__ bias,
                                         const int* __restrict__ cnt,
                                         const int* __restrict__ srcs,
                                         void* __restrict__ outp,
                                         int id) {
  int lane = threadIdx.x & 63;
  int g = lane >> 4, l16 = lane & 15;
  int b = id & 7, n = id >> 3;
  int deg = cnt[n]; if (deg > BUCKET) deg = BUCKET;
  int off0 = n * BUCKET;
  int rbase = b * N_NODES;
  float er_n = er[rbase + n];

  constexpr int J = (F == 128) ? 8 : 4;  // features per 16-lane group member
  float acc[J];
#pragma unroll
  for (int j = 0; j < J; j++) acc[j] = 0.f;
  float lsum = 0.f;

  for (int c = 0; c < deg; c += 64) {
    int j = c + lane;
    int s_my = 0;
    float w_my = 0.f;
    if (j < deg) {
      s_my = srcs[off0 + j];
      float e = el[rbase + s_my] + er_n;
      e = e > 0.f ? e : NEG_SLOPE * e;
      w_my = __expf(e);   // no max pass: |e|<=~10, softmax shift-invariant
      lsum += w_my;
    }
    int cl = deg - c; if (cl > 64) cl = 64;
    for (int k4 = 0; k4 < cl; k4 += 4) {
      int e_idx = k4 + g;
      float wk = __shfl(w_my, e_idx, 64);   // full-convergence shfl (0 for phantom edges)
      int sk = __shfl(s_my, e_idx, 64);
      if (F == 128) {
        uint4 zw = *(const uint4*)((const ushort_t*)z + (size_t)(rbase + sk) * F + l16 * 8);
        acc[0] += wk * bf16_to_f32((ushort_t)(zw.x & 0xFFFF));
        acc[1] += wk * bf16_to_f32((ushort_t)(zw.x >> 16));
        acc[2] += wk * bf16_to_f32((ushort_t)(zw.y & 0xFFFF));
        acc[3] += wk * bf16_to_f32((ushort_t)(zw.y >> 16));
        acc[4] += wk * bf16_to_f32((ushort_t)(zw.z & 0xFFFF));
        acc[5] += wk * bf16_to_f32((ushort_t)(zw.z >> 16));
        acc[6] += wk * bf16_to_f32((ushort_t)(zw.w & 0xFFFF));
        acc[7] += wk * bf16_to_f32((ushort_t)(zw.w >> 16));
      } else {
        uint2 zw = *(const uint2*)((const ushort_t*)z + (size_t)(rbase + sk) * F + l16 * 4);
        acc[0] += wk * bf16_to_f32((ushort_t)(zw.x & 0xFFFF));
        acc[1] += wk * bf16_to_f32((ushort_t)(zw.x >> 16));
        acc[2] += wk * bf16_to_f32((ushort_t)(zw.y & 0xFFFF));
        acc[3] += wk * bf16_to_f32((ushort_t)(zw.y >> 16));
      }
    }
  }
  // combine the 4 edge-groups
#pragma unroll
  for (int j = 0; j < J; j++) {
    acc[j] += __shfl_xor(acc[j], 16, 64);
    acc[j] += __shfl_xor(acc[j], 32, 64);
  }
  float sum = lsum;
#pragma unroll
  for (int o = 32; o; o >>= 1) sum += __shfl_xor(sum, o, 64);
  float inv = (deg > 0) ? 1.f / sum : 0.f;

  if (!FINAL) {
    if (g == 0) {
      uint_t pk[4];
#pragma unroll
      for (int p = 0; p < 4; p++) {
        float o0 = acc[2 * p] * inv + bias[l16 * 8 + 2 * p];
        float o1 = acc[2 * p + 1] * inv + bias[l16 * 8 + 2 * p + 1];
        pk[p] = (uint_t)f32_to_bf16(o0) | ((uint_t)f32_to_bf16(o1) << 16);
      }
      *(uint4*)((ushort_t*)outp + (size_t)(rbase + n) * F + l16 * 8) =
          make_uint4(pk[0], pk[1], pk[2], pk[3]);
    }
  } else {
    float o[4];
#pragma unroll
    for (int j = 0; j < 4; j++) o[j] = acc[j] * inv + bias[l16 * 4 + j];
    float mm = fmaxf(fmaxf(o[0], o[1]), fmaxf(o[2], o[3]));
#pragma unroll
    for (int d = 1; d < 16; d <<= 1) mm = fmaxf(mm, __shfl_xor(mm, d, 64));
    float p0 = __expf(o[0] - mm), p1 = __expf(o[1] - mm);
    float p2 = __expf(o[2] - mm), p3 = __expf(o[3] - mm);
    float ss = p0 + p1 + p2 + p3;
#pragma unroll
    for (int d = 1; d < 16; d <<= 1) ss += __shfl_xor(ss, d, 64);
    if (g == 0) {
      float issv = 1.f / ss;
      *(float4*)((float*)outp + (size_t)(rbase + n) * F + l16 * 4) =
          make_float4(p0 * issv, p1 * issv, p2 * issv, p3 * issv);
    }
  }
}

// ---------------- persistent fused kernel: 4 phases, 3 hand-rolled grid barriers ----------
__global__ __launch_bounds__(256, 3) void fused_gat(const float* __restrict__ x,
                                                    const float* __restrict__ al1,
                                                    const float* __restrict__ ar1,
                                                    const float* __restrict__ b1,
                                                    const float* __restrict__ al2,
                                                    const float* __restrict__ ar2,
                                                    const float* __restrict__ b2,
                                                    const int* __restrict__ e_src,
                                                    const int* __restrict__ e_dst,
                                                    char* __restrict__ ws,
                                                    float* __restrict__ outp) {
  // ws layout (proven r15; z2 bf16 overlay as of R1)
  ushort_t* Bp1 = (ushort_t*)ws;                    // 32 KB
  ushort_t* Bp2 = Bp1 + 16384;                      // 16 KB   (ends 49152)
  ushort_t* z1  = (ushort_t*)(ws + 49152);          // 40000*128 bf16 = 10.24 MB
  ushort_t* z2  = (ushort_t*)(ws + 49152);          // overlay: z1 dead after P2 barrier
  ushort_t* h   = (ushort_t*)(ws + 10289152);       // 10.24 MB (ends 20529152)
  float* el1    = (float*)(ws + 20529152);
  float* er1    = el1 + M_ROWS;
  float* el2    = er1 + M_ROWS;
  float* er2    = el2 + M_ROWS;
  int* cnt      = (int*)(ws + 20529152 + 640000);   // 5000 ints
  int* srcs     = cnt + N_NODES;                    // 5000*96 ints (ends 23109152)
  int* bar      = (int*)(ws + 23200000);            // 3 counters, 128B apart

  int bid = blockIdx.x, tid = threadIdx.x;
  int wave = tid >> 6;

  // ---- P1: edge bucket-scatter + layer-1 GEMM (independent work within phase) ----
  {
    int i = bid * 256 + tid;  // 131072 threads cover 80000 edges
    if (i < N_EDGES) {
      int d = e_dst[i];
      int pos = atomicAdd(&cnt[d], 1);
      if (pos < BUCKET) srcs[d * BUCKET + pos] = e_src[i];  // clamp: structurally safe
    }
  }
  for (int tile = bid; tile < M_ROWS / 64; tile += GRID_BLOCKS)
    gemm_tile<HID_DIM, true, true>(x, Bp1, z1, al1, ar1, el1, er1, tile);
  grid_barrier(bar);

  // ---- P2: layer-1 aggregation -> h (bf16). b = bid&7 preserved (GRID_BLOCKS%8==0) ----
  for (int j = 0; j < 20; j++) {
    int id = j * (GRID_BLOCKS * 4) + wave * GRID_BLOCKS + bid;
    if (id < M_ROWS) agg_unit<HID_DIM, false>(z1, el1, er1, b1, cnt, srcs, h, id);
  }
  grid_barrier(bar + 32);

  // ---- P3: layer-2 GEMM (h bf16 in, z2 bf16 out) ----
  for (int tile = bid; tile < M_ROWS / 64; tile += GRID_BLOCKS)
    gemm_tile<OUT_DIM, false, true>(h, Bp2, z2, al2, ar2, el2, er2, tile);
  grid_barrier(bar + 64);

  // ---- P4: layer-2 aggregation + final row softmax -> d_out (fp32) ----
  for (int j = 0; j < 20; j++) {
    int id = j * (GRID_BLOCKS * 4) + wave * GRID_BLOCKS + bid;
    if (id < M_ROWS) agg_unit<OUT_DIM, true>(z2, el2, er2, b2, cnt, srcs, outp, id);
  }
}

extern "C" void kernel_launch(void* const* d_in, const int* in_sizes, int n_in,
                              void* d_out, int out_size, void* d_ws, size_t ws_size,
                              hipStream_t stream) {
  const float* x   = (const float*)d_in[0];
  const float* W1  = (const float*)d_in[1];
  const float* al1 = (const float*)d_in[2];
  const float* ar1 = (const float*)d_in[3];
  const float* b1  = (const float*)d_in[4];
  const float* W2  = (const float*)d_in[5];
  const float* al2 = (const float*)d_in[6];
  const float* ar2 = (const float*)d_in[7];
  const float* b2  = (const float*)d_in[8];
  const int* src = (const int*)d_in[9];
  const int* dst = (const int*)d_in[10];
  char* ws = (char*)d_ws;

  ushort_t* Bp1 = (ushort_t*)ws;
  ushort_t* Bp2 = Bp1 + 16384;
  int* cnt = (int*)(ws + 20529152 + 640000);
  int* bar = (int*)(ws + 23200000);

  // 1) setup: zero cnt + pack W1/W2 + zero barrier counters
  setup_kernel<<<32, 256, 0, stream>>>(W1, W2, cnt, Bp1, Bp2, bar);

  // 2) persistent fused GAT (4 phases, 3 grid barriers)
  fused_gat<<<GRID_BLOCKS, 256, 0, stream>>>(x, al1, ar1, b1, al2, ar2, b2,
                                             src, dst, ws, (float*)d_out);
}

// Round 5
// 150.012 us; speedup vs baseline: 2.6280x; 2.6280x over previous
//
#include <hip/hip_runtime.h>
#include <hip/hip_bf16.h>

#define N_NODES 5000
#define N_EDGES 80000
#define HID_DIM 128
#define OUT_DIM 64
#define BATCH 8
#define M_ROWS 40000
#define NEG_SLOPE 0.2f
#define BUCKET 96   // fixed per-node capacity; deg~Poisson(16), P(>96)~0 (+20 sigma)

// R4 post-mortem: fused persistent kernel = 332us, VALUBusy 9.2%, all pipes idle ->
// pipeline is LATENCY-bound; grid-barrier + threadfence L2-writeback on non-coherent
// XCD L2s is structurally bad. Reverted to proven 5-dispatch (153.1us, R2).
// R5 change: agg gather loop unrolled 4x (16 edges/iter) -> 4 z-row gathers in
// flight per wave instead of 1 (MLP). Accumulation order preserved (bitwise-same).

typedef unsigned short ushort_t;
typedef unsigned int uint_t;
typedef __attribute__((ext_vector_type(8))) short short8;  // 8 bf16 = 4 VGPRs
typedef __attribute__((ext_vector_type(4))) float f32x4;

__device__ __forceinline__ float bf16_to_f32(ushort_t u) {
  return __uint_as_float(((uint_t)u) << 16);
}
__device__ __forceinline__ ushort_t f32_to_bf16(float f) {
  uint_t u = __float_as_uint(f);
  return (ushort_t)((u + 0x7FFF + ((u >> 16) & 1)) >> 16);  // RNE
}

struct __attribute__((aligned(8))) us4 { ushort_t x, y, z, w; };

// ---------------- zero cnt + pack W: independent work, one dispatch (proven r15) ------------
__global__ __launch_bounds__(256) void zero_pack_kernel(const float* __restrict__ W1,
                                                        const float* __restrict__ W2,
                                                        int* __restrict__ cnt,
                                                        ushort_t* __restrict__ Bp1,
                                                        ushort_t* __restrict__ Bp2) {
  int bid = blockIdx.x;
  if (bid < 20) {
    int i = bid * 256 + threadIdx.x;
    if (i < N_NODES) cnt[i] = 0;
    return;
  }
  int gid = (bid - 20) * 256 + threadIdx.x;  // 0..3071
  if (gid >= 3072) return;
  const float* W; ushort_t* Bp; int NC, idx;
  if (gid < 2048) { W = W1; Bp = Bp1; NC = 128; idx = gid; }
  else            { W = W2; Bp = Bp2; NC = 64;  idx = gid - 2048; }
  int l = idx & 63, tt = idx >> 6;
  int T = NC / 16;
  int kc = tt / T, t = tt % T;
  int col = t * 16 + (l & 15);
  int krow = kc * 32 + (l >> 4) * 8;
  short8 vv;
#pragma unroll
  for (int j = 0; j < 8; j++) vv[j] = (short)f32_to_bf16(W[(size_t)(krow + j) * NC + col]);
  *(short8*)(Bp + (size_t)idx * 8) = vv;
}

// ---------------- MFMA GEMM with fused el/er epilogue (proven r10..r15) ----------------
template <int NC, bool A_F32, bool C_BF16, bool SCATTER>
__global__ __launch_bounds__(256) void gemm_mfma(const void* __restrict__ A,
                                                 const ushort_t* __restrict__ Bp,
                                                 void* __restrict__ C,
                                                 const float* __restrict__ al,
                                                 const float* __restrict__ ar,
                                                 float* __restrict__ el,
                                                 float* __restrict__ er,
                                                 const int* __restrict__ e_src,
                                                 const int* __restrict__ e_dst,
                                                 int* __restrict__ cnt,
                                                 int* __restrict__ srcs) {
  if (SCATTER) {
    int tid = threadIdx.x;
    if (tid < 128) {
      int i = blockIdx.x * 128 + tid;   // gridDim=625 -> covers [0,80000)
      int d = e_dst[i];
      int pos = atomicAdd(&cnt[d], 1);
      if (pos < BUCKET) srcs[d * BUCKET + pos] = e_src[i];  // clamp: structurally safe
    }
  }
  constexpr int T = NC / 16;
  int wave = threadIdx.x >> 6, lane = threadIdx.x & 63;
  int q = lane >> 4, m = lane & 15;
  int r0 = blockIdx.x * 64 + wave * 16;
  f32x4 acc[T];
#pragma unroll
  for (int t = 0; t < T; t++)
#pragma unroll
    for (int i = 0; i < 4; i++) acc[t][i] = 0.f;

  const short8* Bp8 = (const short8*)Bp;
  size_t arow = (size_t)(r0 + m) * 128;
#pragma unroll
  for (int kc = 0; kc < 4; kc++) {
    short8 af;
    if (A_F32) {
      const float* Ap = (const float*)A + arow + kc * 32 + q * 8;
      float4 v0 = *(const float4*)Ap;
      float4 v1 = *(const float4*)(Ap + 4);
      af[0] = (short)f32_to_bf16(v0.x); af[1] = (short)f32_to_bf16(v0.y);
      af[2] = (short)f32_to_bf16(v0.z); af[3] = (short)f32_to_bf16(v0.w);
      af[4] = (short)f32_to_bf16(v1.x); af[5] = (short)f32_to_bf16(v1.y);
      af[6] = (short)f32_to_bf16(v1.z); af[7] = (short)f32_to_bf16(v1.w);
    } else {
      const ushort_t* Ap = (const ushort_t*)A + arow + kc * 32 + q * 8;
      us4 a0 = *(const us4*)Ap;
      us4 a1 = *(const us4*)(Ap + 4);
      af[0] = (short)a0.x; af[1] = (short)a0.y; af[2] = (short)a0.z; af[3] = (short)a0.w;
      af[4] = (short)a1.x; af[5] = (short)a1.y; af[6] = (short)a1.z; af[7] = (short)a1.w;
    }
#pragma unroll
    for (int t = 0; t < T; t++) {
      short8 bf = Bp8[(kc * T + t) * 64 + lane];
      acc[t] = __builtin_amdgcn_mfma_f32_16x16x32_bf16(af, bf, acc[t], 0, 0, 0);
    }
  }
  // fused el/er from fp32 acc (pre-rounding), reduce over 16 m-lanes
  float sl[4] = {0.f, 0.f, 0.f, 0.f}, sr[4] = {0.f, 0.f, 0.f, 0.f};
#pragma unroll
  for (int t = 0; t < T; t++) {
    float alv = al[t * 16 + m];
    float arv = ar[t * 16 + m];
#pragma unroll
    for (int i = 0; i < 4; i++) { sl[i] += acc[t][i] * alv; sr[i] += acc[t][i] * arv; }
  }
#pragma unroll
  for (int o = 1; o < 16; o <<= 1) {
#pragma unroll
    for (int i = 0; i < 4; i++) {
      sl[i] += __shfl_xor(sl[i], o, 64);
      sr[i] += __shfl_xor(sr[i], o, 64);
    }
  }
  if (m == 0) {
#pragma unroll
    for (int i = 0; i < 4; i++) {
      el[r0 + q * 4 + i] = sl[i];
      er[r0 + q * 4 + i] = sr[i];
    }
  }
  // C store: row = r0 + q*4 + i, col = t*16 + m (m89-verified, proven r6..r15)
#pragma unroll
  for (int t = 0; t < T; t++)
#pragma unroll
    for (int i = 0; i < 4; i++) {
      size_t off = (size_t)(r0 + q * 4 + i) * NC + t * 16 + m;
      if (C_BF16) ((ushort_t*)C)[off] = f32_to_bf16(acc[t][i]);
      else        ((float*)C)[off] = acc[t][i];
    }
}

// ---------------- edge-softmax aggregation (R5: 4x-unrolled gather loop, MLP=4) ----------
template <int F, bool FINAL>
__global__ __launch_bounds__(256) void agg_kernel(const void* __restrict__ z,
                                                  const float* __restrict__ el,
                                                  const float* __restrict__ er,
                                                  const float* __restrict__ bias,
                                                  const int* __restrict__ cnt,
                                                  const int* __restrict__ srcs,
                                                  void* __restrict__ outp) {
  int id = (threadIdx.x >> 6) * gridDim.x + blockIdx.x;  // gridDim%8==0 keeps batch=XCD pairing
  int lane = threadIdx.x & 63;
  int g = lane >> 4, l16 = lane & 15;
  int b = id & 7, n = id >> 3;
  int deg = cnt[n]; if (deg > BUCKET) deg = BUCKET;
  int off0 = n * BUCKET;
  int rbase = b * N_NODES;
  float er_n = er[rbase + n];

  constexpr int J = (F == 128) ? 8 : 4;  // features per 16-lane group member
  float acc[J];
#pragma unroll
  for (int j = 0; j < J; j++) acc[j] = 0.f;
  float lsum = 0.f;

  for (int c = 0; c < deg; c += 64) {
    int j = c + lane;
    int s_my = 0;
    float w_my = 0.f;
    if (j < deg) {
      s_my = srcs[off0 + j];
      float e = el[rbase + s_my] + er_n;
      e = e > 0.f ? e : NEG_SLOPE * e;
      w_my = __expf(e);   // no max pass: |e|<=~10, softmax shift-invariant
      lsum += w_my;
    }
    int cl = deg - c; if (cl > 64) cl = 64;
    // R5: macro-iterate 16 edges (4 sub-steps of 4); issue all 4 gathers before any FMA.
    // Phantom slots (k0+u*4 >= cl): w=0, s=0 -> harmless row-0 load, zero contribution.
    // Accumulation order identical to the proven sequential loop (u ascending).
    for (int k0 = 0; k0 < cl; k0 += 16) {
      float wk[4]; int sk[4];
#pragma unroll
      for (int u = 0; u < 4; u++) {
        int e_idx = k0 + u * 4 + g;
        wk[u] = __shfl(w_my, e_idx, 64);   // full-convergence shfl (0 for phantom edges)
        sk[u] = __shfl(s_my, e_idx, 64);
      }
      if (F == 128) {
        uint4 zw[4];
#pragma unroll
        for (int u = 0; u < 4; u++)
          zw[u] = *(const uint4*)((const ushort_t*)z + (size_t)(rbase + sk[u]) * F + l16 * 8);
#pragma unroll
        for (int u = 0; u < 4; u++) {
          acc[0] += wk[u] * bf16_to_f32((ushort_t)(zw[u].x & 0xFFFF));
          acc[1] += wk[u] * bf16_to_f32((ushort_t)(zw[u].x >> 16));
          acc[2] += wk[u] * bf16_to_f32((ushort_t)(zw[u].y & 0xFFFF));
          acc[3] += wk[u] * bf16_to_f32((ushort_t)(zw[u].y >> 16));
          acc[4] += wk[u] * bf16_to_f32((ushort_t)(zw[u].z & 0xFFFF));
          acc[5] += wk[u] * bf16_to_f32((ushort_t)(zw[u].z >> 16));
          acc[6] += wk[u] * bf16_to_f32((ushort_t)(zw[u].w & 0xFFFF));
          acc[7] += wk[u] * bf16_to_f32((ushort_t)(zw[u].w >> 16));
        }
      } else {
        uint2 zw[4];
#pragma unroll
        for (int u = 0; u < 4; u++)
          zw[u] = *(const uint2*)((const ushort_t*)z + (size_t)(rbase + sk[u]) * F + l16 * 4);
#pragma unroll
        for (int u = 0; u < 4; u++) {
          acc[0] += wk[u] * bf16_to_f32((ushort_t)(zw[u].x & 0xFFFF));
          acc[1] += wk[u] * bf16_to_f32((ushort_t)(zw[u].x >> 16));
          acc[2] += wk[u] * bf16_to_f32((ushort_t)(zw[u].y & 0xFFFF));
          acc[3] += wk[u] * bf16_to_f32((ushort_t)(zw[u].y >> 16));
        }
      }
    }
  }
  // combine the 4 edge-groups
#pragma unroll
  for (int j = 0; j < J; j++) {
    acc[j] += __shfl_xor(acc[j], 16, 64);
    acc[j] += __shfl_xor(acc[j], 32, 64);
  }
  float sum = lsum;
#pragma unroll
  for (int o = 32; o; o >>= 1) sum += __shfl_xor(sum, o, 64);
  float inv = (deg > 0) ? 1.f / sum : 0.f;

  if (!FINAL) {
    if (g == 0) {
      uint_t pk[4];
#pragma unroll
      for (int p = 0; p < 4; p++) {
        float o0 = acc[2 * p] * inv + bias[l16 * 8 + 2 * p];
        float o1 = acc[2 * p + 1] * inv + bias[l16 * 8 + 2 * p + 1];
        pk[p] = (uint_t)f32_to_bf16(o0) | ((uint_t)f32_to_bf16(o1) << 16);
      }
      *(uint4*)((ushort_t*)outp + (size_t)(rbase + n) * F + l16 * 8) =
          make_uint4(pk[0], pk[1], pk[2], pk[3]);
    }
  } else {
    float o[4];
#pragma unroll
    for (int j = 0; j < 4; j++) o[j] = acc[j] * inv + bias[l16 * 4 + j];
    float mm = fmaxf(fmaxf(o[0], o[1]), fmaxf(o[2], o[3]));
#pragma unroll
    for (int d = 1; d < 16; d <<= 1) mm = fmaxf(mm, __shfl_xor(mm, d, 64));
    float p0 = __expf(o[0] - mm), p1 = __expf(o[1] - mm);
    float p2 = __expf(o[2] - mm), p3 = __expf(o[3] - mm);
    float ss = p0 + p1 + p2 + p3;
#pragma unroll
    for (int d = 1; d < 16; d <<= 1) ss += __shfl_xor(ss, d, 64);
    if (g == 0) {
      float issv = 1.f / ss;
      *(float4*)((float*)outp + (size_t)(rbase + n) * F + l16 * 4) =
          make_float4(p0 * issv, p1 * issv, p2 * issv, p3 * issv);
    }
  }
}

extern "C" void kernel_launch(void* const* d_in, const int* in_sizes, int n_in,
                              void* d_out, int out_size, void* d_ws, size_t ws_size,
                              hipStream_t stream) {
  const float* x   = (const float*)d_in[0];
  const float* W1  = (const float*)d_in[1];
  const float* al1 = (const float*)d_in[2];
  const float* ar1 = (const float*)d_in[3];
  const float* b1  = (const float*)d_in[4];
  const float* W2  = (const float*)d_in[5];
  const float* al2 = (const float*)d_in[6];
  const float* ar2 = (const float*)d_in[7];
  const float* b2  = (const float*)d_in[8];
  const int* src = (const int*)d_in[9];
  const int* dst = (const int*)d_in[10];

  // ws layout (proven r15; z2 bf16 overlay as of R1)
  char* base = (char*)d_ws;
  ushort_t* Bp1 = (ushort_t*)base;                   // 32 KB
  ushort_t* Bp2 = Bp1 + 16384;                       // 16 KB    (ends 49152)
  ushort_t* z1  = (ushort_t*)(base + 49152);         // 40000*128 bf16 = 10.24 MB
  ushort_t* z2  = (ushort_t*)(base + 49152);         // overlay: 40000*64 bf16 (z1 dead by then)
  ushort_t* h   = (ushort_t*)(base + 10289152);      // 10.24 MB (ends 20529152)
  float* el1    = (float*)(base + 20529152);
  float* er1    = el1 + M_ROWS;
  float* el2    = er1 + M_ROWS;
  float* er2    = el2 + M_ROWS;
  int* cnt      = (int*)(base + 20529152 + 640000);  // 5000 ints
  int* srcs     = cnt + N_NODES;                     // 5000*96 ints = 1.92 MB

  // 1) zero cnt + pack W
  zero_pack_kernel<<<32, 256, 0, stream>>>(W1, W2, cnt, Bp1, Bp2);

  // 2) layer-1 GEMM + fused el/er + edge bucket-scatter prologue
  gemm_mfma<HID_DIM, true, true, true><<<M_ROWS / 64, 256, 0, stream>>>(
      x, Bp1, z1, al1, ar1, el1, er1, src, dst, cnt, srcs);

  // 3) layer-1 aggregation -> h (bf16)
  agg_kernel<HID_DIM, false><<<M_ROWS / 4, 256, 0, stream>>>(z1, el1, er1, b1, cnt, srcs, h);

  // 4) layer-2 GEMM + fused el/er (C bf16)
  gemm_mfma<OUT_DIM, false, true, false><<<M_ROWS / 64, 256, 0, stream>>>(
      h, Bp2, z2, al2, ar2, el2, er2, nullptr, nullptr, nullptr, nullptr);

  // 5) layer-2 aggregation + final row softmax -> d_out (fp32)
  agg_kernel<OUT_DIM, true><<<M_ROWS / 4, 256, 0, stream>>>(z2, el2, er2, b2, cnt, srcs, d_out);
}

// Round 6
// 143.296 us; speedup vs baseline: 2.7512x; 1.0469x over previous
//
#include <hip/hip_runtime.h>
#include <hip/hip_bf16.h>

#define N_NODES 5000
#define N_EDGES 80000
#define HID_DIM 128
#define OUT_DIM 64
#define BATCH 8
#define M_ROWS 40000
#define NEG_SLOPE 0.2f
#define BUCKET 96   // fixed per-node capacity; deg~Poisson(16), P(>96)~0 (+20 sigma)

// R6: algebraic re-association. z2 = A1·(z1@W2) + b1@W2  ->  gemm2 fused into gemm1
// via LDS (z1 never hits global); agg1 aggregates 64-dim y (+2 scalars for el2/er2)
// instead of 128-dim z1; final agg uses bias cb = b1@W2 + b2 (A2 row-sums = 1).
// 4 dispatches. Proven components: MFMA C-layout (m89), el/er epilogue, agg structure,
// R5 4x-unrolled gather, R1 bf16 intermediates.

typedef unsigned short ushort_t;
typedef unsigned int uint_t;
typedef __attribute__((ext_vector_type(8))) short short8;  // 8 bf16 = 4 VGPRs
typedef __attribute__((ext_vector_type(4))) float f32x4;

__device__ __forceinline__ float bf16_to_f32(ushort_t u) {
  return __uint_as_float(((uint_t)u) << 16);
}
__device__ __forceinline__ ushort_t f32_to_bf16(float f) {
  uint_t u = __float_as_uint(f);
  return (ushort_t)((u + 0x7FFF + ((u >> 16) & 1)) >> 16);  // RNE
}

struct __attribute__((aligned(8))) us4 { ushort_t x, y, z, w; };

// ws layout (R6)
#define OFF_BP1   0u          // 32 KB
#define OFF_BP2   32768u      // 16 KB
#define OFF_CMETA 49152u      // 2 floats (cl2, cr2)
#define OFF_CB    49184u      // 64 floats (c + b2)
#define OFF_Y     65536u      // 40000*64 bf16 = 5.12 MB
#define OFF_EY    5185536u    // 40000 float2 = 320 KB
#define OFF_W     5505536u    // 40000*64 bf16 = 5.12 MB
#define OFF_EL1   10625536u
#define OFF_ER1   10785536u
#define OFF_EL2   10945536u
#define OFF_ER2   11105536u
#define OFF_CNT   11265536u
#define OFF_SRCS  11285536u   // ends 13,205,536

// ---------------- setup: zero cnt + pack W1/W2 + c = b1@W2 metadata ----------------
__global__ __launch_bounds__(256) void zero_pack_kernel(const float* __restrict__ W1,
                                                        const float* __restrict__ W2,
                                                        const float* __restrict__ b1,
                                                        const float* __restrict__ b2,
                                                        const float* __restrict__ al2,
                                                        const float* __restrict__ ar2,
                                                        int* __restrict__ cnt,
                                                        ushort_t* __restrict__ Bp1,
                                                        ushort_t* __restrict__ Bp2,
                                                        float* __restrict__ cmeta,
                                                        float* __restrict__ cb) {
  int bid = blockIdx.x;
  if (bid < 20) {
    int i = bid * 256 + threadIdx.x;
    if (i < N_NODES) cnt[i] = 0;
    return;
  }
  if (bid == 32) {
    int f = threadIdx.x;
    if (f < 64) {
      float c = 0.f;
#pragma unroll 8
      for (int k = 0; k < 128; k++) c += b1[k] * W2[(size_t)k * 64 + f];
      cb[f] = c + b2[f];
      float cl = c * al2[f], cr = c * ar2[f];
#pragma unroll
      for (int o = 32; o; o >>= 1) {
        cl += __shfl_xor(cl, o, 64);
        cr += __shfl_xor(cr, o, 64);
      }
      if (f == 0) { cmeta[0] = cl; cmeta[1] = cr; }
    }
    return;
  }
  int gid = (bid - 20) * 256 + threadIdx.x;  // 0..3071
  if (gid >= 3072) return;
  const float* W; ushort_t* Bp; int NC, idx;
  if (gid < 2048) { W = W1; Bp = Bp1; NC = 128; idx = gid; }
  else            { W = W2; Bp = Bp2; NC = 64;  idx = gid - 2048; }
  int l = idx & 63, tt = idx >> 6;
  int T = NC / 16;
  int kc = tt / T, t = tt % T;
  int col = t * 16 + (l & 15);
  int krow = kc * 32 + (l >> 4) * 8;
  short8 vv;
#pragma unroll
  for (int j = 0; j < 8; j++) vv[j] = (short)f32_to_bf16(W[(size_t)(krow + j) * NC + col]);
  *(short8*)(Bp + (size_t)idx * 8) = vv;
}

// ---------------- fused gemm: z1 = x@W1 (LDS only) -> y = z1@W2; el1/er1 + ey; scatter ----
__global__ __launch_bounds__(256) void gemm_fused(const float* __restrict__ A,
                                                  const ushort_t* __restrict__ Bp1,
                                                  const ushort_t* __restrict__ Bp2,
                                                  const float* __restrict__ al1,
                                                  const float* __restrict__ ar1,
                                                  const float* __restrict__ al2,
                                                  const float* __restrict__ ar2,
                                                  float* __restrict__ el1,
                                                  float* __restrict__ er1,
                                                  ushort_t* __restrict__ y,
                                                  float2* __restrict__ ey,
                                                  const int* __restrict__ e_src,
                                                  const int* __restrict__ e_dst,
                                                  int* __restrict__ cnt,
                                                  int* __restrict__ srcs) {
  // edge bucket-scatter prologue (gridDim=625 x 128 = 80000 exactly)
  {
    int tid = threadIdx.x;
    if (tid < 128) {
      int i = blockIdx.x * 128 + tid;
      int d = e_dst[i];
      int pos = atomicAdd(&cnt[d], 1);
      if (pos < BUCKET) srcs[d * BUCKET + pos] = e_src[i];  // clamp: structurally safe
    }
  }
  __shared__ ushort_t lds[64 * 128];  // 16 KB, z1 tile bf16, XOR-swizzled rows
  int wave = threadIdx.x >> 6, lane = threadIdx.x & 63;
  int q = lane >> 4, m = lane & 15;
  int r0 = blockIdx.x * 64 + wave * 16;

  // ---- stage 1: z1_tile = x_tile @ W1 (T=8) ----
  f32x4 acc[8];
#pragma unroll
  for (int t = 0; t < 8; t++)
#pragma unroll
    for (int i = 0; i < 4; i++) acc[t][i] = 0.f;
  const short8* B1 = (const short8*)Bp1;
  size_t arow = (size_t)(r0 + m) * 128;
#pragma unroll
  for (int kc = 0; kc < 4; kc++) {
    const float* Ap = A + arow + kc * 32 + q * 8;
    float4 v0 = *(const float4*)Ap;
    float4 v1 = *(const float4*)(Ap + 4);
    short8 af;
    af[0] = (short)f32_to_bf16(v0.x); af[1] = (short)f32_to_bf16(v0.y);
    af[2] = (short)f32_to_bf16(v0.z); af[3] = (short)f32_to_bf16(v0.w);
    af[4] = (short)f32_to_bf16(v1.x); af[5] = (short)f32_to_bf16(v1.y);
    af[6] = (short)f32_to_bf16(v1.z); af[7] = (short)f32_to_bf16(v1.w);
#pragma unroll
    for (int t = 0; t < 8; t++)
      acc[t] = __builtin_amdgcn_mfma_f32_16x16x32_bf16(af, B1[(kc * 8 + t) * 64 + lane], acc[t], 0, 0, 0);
  }
  // el1/er1 epilogue (fp32 acc, reduce over 16 m-lanes) — proven pattern
  {
    float sl[4] = {0.f, 0.f, 0.f, 0.f}, sr[4] = {0.f, 0.f, 0.f, 0.f};
#pragma unroll
    for (int t = 0; t < 8; t++) {
      float alv = al1[t * 16 + m], arv = ar1[t * 16 + m];
#pragma unroll
      for (int i = 0; i < 4; i++) { sl[i] += acc[t][i] * alv; sr[i] += acc[t][i] * arv; }
    }
#pragma unroll
    for (int o = 1; o < 16; o <<= 1)
#pragma unroll
      for (int i = 0; i < 4; i++) {
        sl[i] += __shfl_xor(sl[i], o, 64);
        sr[i] += __shfl_xor(sr[i], o, 64);
      }
    if (m == 0)
#pragma unroll
      for (int i = 0; i < 4; i++) {
        el1[r0 + q * 4 + i] = sl[i];
        er1[r0 + q * 4 + i] = sr[i];
      }
  }
  // stage-1 -> LDS (bf16, RNE): row = q*4+i+wave*16, col = t*16+m; byte ^= (row&7)<<4
#pragma unroll
  for (int t = 0; t < 8; t++)
#pragma unroll
    for (int i = 0; i < 4; i++) {
      int row = q * 4 + i + wave * 16;
      int byte = row * 256 + (t * 16 + m) * 2;
      lds[(byte ^ ((row & 7) << 4)) >> 1] = f32_to_bf16(acc[t][i]);
    }
  __syncthreads();

  // ---- stage 2: y_tile = z1_tile(bf16) @ W2 (T=4) ----
  f32x4 acc2[4];
#pragma unroll
  for (int t = 0; t < 4; t++)
#pragma unroll
    for (int i = 0; i < 4; i++) acc2[t][i] = 0.f;
  const short8* B2 = (const short8*)Bp2;
  int row2 = wave * 16 + m;
#pragma unroll
  for (int kc = 0; kc < 4; kc++) {
    int byte = row2 * 256 + kc * 64 + q * 16;      // 16B-aligned; XOR keeps bits 0-3
    short8 af2 = *(const short8*)((const char*)lds + (byte ^ ((row2 & 7) << 4)));
#pragma unroll
    for (int t = 0; t < 4; t++)
      acc2[t] = __builtin_amdgcn_mfma_f32_16x16x32_bf16(af2, B2[(kc * 4 + t) * 64 + lane], acc2[t], 0, 0, 0);
  }
  // ey epilogue (y·al2, y·ar2 per row, fp32 pre-rounding)
  {
    float sl[4] = {0.f, 0.f, 0.f, 0.f}, sr[4] = {0.f, 0.f, 0.f, 0.f};
#pragma unroll
    for (int t = 0; t < 4; t++) {
      float alv = al2[t * 16 + m], arv = ar2[t * 16 + m];
#pragma unroll
      for (int i = 0; i < 4; i++) { sl[i] += acc2[t][i] * alv; sr[i] += acc2[t][i] * arv; }
    }
#pragma unroll
    for (int o = 1; o < 16; o <<= 1)
#pragma unroll
      for (int i = 0; i < 4; i++) {
        sl[i] += __shfl_xor(sl[i], o, 64);
        sr[i] += __shfl_xor(sr[i], o, 64);
      }
    if (m == 0)
#pragma unroll
      for (int i = 0; i < 4; i++) ey[r0 + q * 4 + i] = make_float2(sl[i], sr[i]);
  }
  // y store: row = r0 + q*4 + i, col = t*16 + m (m89-verified layout)
#pragma unroll
  for (int t = 0; t < 4; t++)
#pragma unroll
    for (int i = 0; i < 4; i++)
      y[(size_t)(r0 + q * 4 + i) * 64 + t * 16 + m] = f32_to_bf16(acc2[t][i]);
}

// ---------------- mid aggregation: w = A1·y ; el2/er2 = A1·ey + c·a (scalars) ----------
__global__ __launch_bounds__(256) void agg_mid(const ushort_t* __restrict__ y,
                                               const float2* __restrict__ ey,
                                               const float* __restrict__ el,
                                               const float* __restrict__ er,
                                               const int* __restrict__ cnt,
                                               const int* __restrict__ srcs,
                                               const float* __restrict__ cmeta,
                                               ushort_t* __restrict__ w,
                                               float* __restrict__ el2,
                                               float* __restrict__ er2) {
  int id = (threadIdx.x >> 6) * gridDim.x + blockIdx.x;  // gridDim%8==0: batch=XCD pairing
  int lane = threadIdx.x & 63;
  int g = lane >> 4, l16 = lane & 15;
  int b = id & 7, n = id >> 3;
  int deg = cnt[n]; if (deg > BUCKET) deg = BUCKET;
  int off0 = n * BUCKET;
  int rbase = b * N_NODES;
  float er_n = er[rbase + n];

  float acc[4] = {0.f, 0.f, 0.f, 0.f};
  float lsum = 0.f, sl2 = 0.f, sr2 = 0.f;

  for (int c = 0; c < deg; c += 64) {
    int j = c + lane;
    int s_my = 0;
    float w_my = 0.f;
    if (j < deg) {
      s_my = srcs[off0 + j];
      float e = el[rbase + s_my] + er_n;
      e = e > 0.f ? e : NEG_SLOPE * e;
      w_my = __expf(e);
      lsum += w_my;
      float2 ev = ey[rbase + s_my];
      sl2 += w_my * ev.x;
      sr2 += w_my * ev.y;
    }
    int cl = deg - c; if (cl > 64) cl = 64;
    for (int k0 = 0; k0 < cl; k0 += 16) {   // R5 4x-unrolled gather (MLP=4)
      float wk[4]; int sk[4];
#pragma unroll
      for (int u = 0; u < 4; u++) {
        int e_idx = k0 + u * 4 + g;
        wk[u] = __shfl(w_my, e_idx, 64);
        sk[u] = __shfl(s_my, e_idx, 64);
      }
      uint2 zw[4];
#pragma unroll
      for (int u = 0; u < 4; u++)
        zw[u] = *(const uint2*)(y + (size_t)(rbase + sk[u]) * 64 + l16 * 4);
#pragma unroll
      for (int u = 0; u < 4; u++) {
        acc[0] += wk[u] * bf16_to_f32((ushort_t)(zw[u].x & 0xFFFF));
        acc[1] += wk[u] * bf16_to_f32((ushort_t)(zw[u].x >> 16));
        acc[2] += wk[u] * bf16_to_f32((ushort_t)(zw[u].y & 0xFFFF));
        acc[3] += wk[u] * bf16_to_f32((ushort_t)(zw[u].y >> 16));
      }
    }
  }
#pragma unroll
  for (int j = 0; j < 4; j++) {
    acc[j] += __shfl_xor(acc[j], 16, 64);
    acc[j] += __shfl_xor(acc[j], 32, 64);
  }
  float sum = lsum;
#pragma unroll
  for (int o = 32; o; o >>= 1) {
    sum += __shfl_xor(sum, o, 64);
    sl2 += __shfl_xor(sl2, o, 64);
    sr2 += __shfl_xor(sr2, o, 64);
  }
  float inv = (deg > 0) ? 1.f / sum : 0.f;

  if (g == 0) {
    uint_t pk0 = (uint_t)f32_to_bf16(acc[0] * inv) | ((uint_t)f32_to_bf16(acc[1] * inv) << 16);
    uint_t pk1 = (uint_t)f32_to_bf16(acc[2] * inv) | ((uint_t)f32_to_bf16(acc[3] * inv) << 16);
    *(uint2*)(w + (size_t)(rbase + n) * 64 + l16 * 4) = make_uint2(pk0, pk1);
  }
  if (lane == 0) {
    el2[rbase + n] = sl2 * inv + cmeta[0];
    er2[rbase + n] = sr2 * inv + cmeta[1];
  }
}

// ---------------- final aggregation: o = A2·w + cb, row softmax -> fp32 out ----------
__global__ __launch_bounds__(256) void agg_fin(const ushort_t* __restrict__ w,
                                               const float* __restrict__ el,
                                               const float* __restrict__ er,
                                               const float* __restrict__ cb,
                                               const int* __restrict__ cnt,
                                               const int* __restrict__ srcs,
                                               float* __restrict__ outp) {
  int id = (threadIdx.x >> 6) * gridDim.x + blockIdx.x;
  int lane = threadIdx.x & 63;
  int g = lane >> 4, l16 = lane & 15;
  int b = id & 7, n = id >> 3;
  int deg = cnt[n]; if (deg > BUCKET) deg = BUCKET;
  int off0 = n * BUCKET;
  int rbase = b * N_NODES;
  float er_n = er[rbase + n];

  float acc[4] = {0.f, 0.f, 0.f, 0.f};
  float lsum = 0.f;

  for (int c = 0; c < deg; c += 64) {
    int j = c + lane;
    int s_my = 0;
    float w_my = 0.f;
    if (j < deg) {
      s_my = srcs[off0 + j];
      float e = el[rbase + s_my] + er_n;
      e = e > 0.f ? e : NEG_SLOPE * e;
      w_my = __expf(e);
      lsum += w_my;
    }
    int cl = deg - c; if (cl > 64) cl = 64;
    for (int k0 = 0; k0 < cl; k0 += 16) {
      float wk[4]; int sk[4];
#pragma unroll
      for (int u = 0; u < 4; u++) {
        int e_idx = k0 + u * 4 + g;
        wk[u] = __shfl(w_my, e_idx, 64);
        sk[u] = __shfl(s_my, e_idx, 64);
      }
      uint2 zw[4];
#pragma unroll
      for (int u = 0; u < 4; u++)
        zw[u] = *(const uint2*)(w + (size_t)(rbase + sk[u]) * 64 + l16 * 4);
#pragma unroll
      for (int u = 0; u < 4; u++) {
        acc[0] += wk[u] * bf16_to_f32((ushort_t)(zw[u].x & 0xFFFF));
        acc[1] += wk[u] * bf16_to_f32((ushort_t)(zw[u].x >> 16));
        acc[2] += wk[u] * bf16_to_f32((ushort_t)(zw[u].y & 0xFFFF));
        acc[3] += wk[u] * bf16_to_f32((ushort_t)(zw[u].y >> 16));
      }
    }
  }
#pragma unroll
  for (int j = 0; j < 4; j++) {
    acc[j] += __shfl_xor(acc[j], 16, 64);
    acc[j] += __shfl_xor(acc[j], 32, 64);
  }
  float sum = lsum;
#pragma unroll
  for (int o = 32; o; o >>= 1) sum += __shfl_xor(sum, o, 64);
  float inv = (deg > 0) ? 1.f / sum : 0.f;

  float o[4];
#pragma unroll
  for (int j = 0; j < 4; j++) o[j] = acc[j] * inv + cb[l16 * 4 + j];
  float mm = fmaxf(fmaxf(o[0], o[1]), fmaxf(o[2], o[3]));
#pragma unroll
  for (int d = 1; d < 16; d <<= 1) mm = fmaxf(mm, __shfl_xor(mm, d, 64));
  float p0 = __expf(o[0] - mm), p1 = __expf(o[1] - mm);
  float p2 = __expf(o[2] - mm), p3 = __expf(o[3] - mm);
  float ss = p0 + p1 + p2 + p3;
#pragma unroll
  for (int d = 1; d < 16; d <<= 1) ss += __shfl_xor(ss, d, 64);
  if (g == 0) {
    float issv = 1.f / ss;
    *(float4*)(outp + (size_t)(rbase + n) * 64 + l16 * 4) =
        make_float4(p0 * issv, p1 * issv, p2 * issv, p3 * issv);
  }
}

extern "C" void kernel_launch(void* const* d_in, const int* in_sizes, int n_in,
                              void* d_out, int out_size, void* d_ws, size_t ws_size,
                              hipStream_t stream) {
  const float* x   = (const float*)d_in[0];
  const float* W1  = (const float*)d_in[1];
  const float* al1 = (const float*)d_in[2];
  const float* ar1 = (const float*)d_in[3];
  const float* b1  = (const float*)d_in[4];
  const float* W2  = (const float*)d_in[5];
  const float* al2 = (const float*)d_in[6];
  const float* ar2 = (const float*)d_in[7];
  const float* b2  = (const float*)d_in[8];
  const int* src = (const int*)d_in[9];
  const int* dst = (const int*)d_in[10];

  char* base = (char*)d_ws;
  ushort_t* Bp1  = (ushort_t*)(base + OFF_BP1);
  ushort_t* Bp2  = (ushort_t*)(base + OFF_BP2);
  float*    cmeta= (float*)(base + OFF_CMETA);
  float*    cb   = (float*)(base + OFF_CB);
  ushort_t* y    = (ushort_t*)(base + OFF_Y);
  float2*   ey   = (float2*)(base + OFF_EY);
  ushort_t* w    = (ushort_t*)(base + OFF_W);
  float* el1 = (float*)(base + OFF_EL1);
  float* er1 = (float*)(base + OFF_ER1);
  float* el2 = (float*)(base + OFF_EL2);
  float* er2 = (float*)(base + OFF_ER2);
  int* cnt  = (int*)(base + OFF_CNT);
  int* srcs = (int*)(base + OFF_SRCS);

  // 1) setup: zero cnt + pack W1/W2 + c-metadata (c = b1@W2; cb = c + b2; cl2/cr2)
  zero_pack_kernel<<<33, 256, 0, stream>>>(W1, W2, b1, b2, al2, ar2, cnt, Bp1, Bp2, cmeta, cb);

  // 2) fused GEMM: x@W1 -> LDS -> @W2 = y; el1/er1 + ey; edge scatter
  gemm_fused<<<M_ROWS / 64, 256, 0, stream>>>(x, Bp1, Bp2, al1, ar1, al2, ar2,
                                              el1, er1, y, ey, src, dst, cnt, srcs);

  // 3) mid aggregation: w = A1·y ; el2/er2
  agg_mid<<<M_ROWS / 4, 256, 0, stream>>>(y, ey, el1, er1, cnt, srcs, cmeta, w, el2, er2);

  // 4) final aggregation + row softmax
  agg_fin<<<M_ROWS / 4, 256, 0, stream>>>(w, el2, er2, cb, cnt, srcs, (float*)d_out);
}